// Round 1
// baseline (370.419 us; speedup 1.0000x reference)
//
#include <hip/hip_runtime.h>
#include <hip/hip_bf16.h>

#define HH 8
#define DP 16
#define DD 128
#define SLOPE 0.2f

// ---------------------------------------------------------------------------
// K1: fused projection  fs = x@w_src + b_src ; fd = x@w_dst + b_dst
// block = 256 threads: tid<128 -> fs column tid, tid>=128 -> fd column tid-128
// BM=32 nodes per block staged in LDS; LDS reads are wave-broadcast (free).
// ---------------------------------------------------------------------------
#define BM 32
__global__ __launch_bounds__(256) void proj_kernel(
    const float* __restrict__ x,
    const float* __restrict__ w_src, const float* __restrict__ b_src,
    const float* __restrict__ w_dst, const float* __restrict__ b_dst,
    float* __restrict__ fs, float* __restrict__ fd, int n) {
  __shared__ float xs[BM][DD];
  const int tid = threadIdx.x;
  const int block0 = blockIdx.x * BM;

  // stage x tile: BM*128 floats = 1024 float4, 256 threads -> 4 each
  for (int i = tid; i < BM * DD / 4; i += 256) {
    int m = i >> 5;              // /32 float4 per row
    int k = (i & 31) << 2;
    int node = block0 + m;
    float4 v = make_float4(0.f, 0.f, 0.f, 0.f);
    if (node < n) v = *reinterpret_cast<const float4*>(x + (size_t)node * DD + k);
    *reinterpret_cast<float4*>(&xs[m][k]) = v;
  }
  __syncthreads();

  const float* w = (tid < DD) ? w_src : w_dst;
  const int c = tid & (DD - 1);

  float acc[BM];
#pragma unroll
  for (int m = 0; m < BM; ++m) acc[m] = 0.f;

  for (int k = 0; k < DD; k += 4) {
    float w0 = w[(k + 0) * DD + c];
    float w1 = w[(k + 1) * DD + c];
    float w2 = w[(k + 2) * DD + c];
    float w3 = w[(k + 3) * DD + c];
#pragma unroll
    for (int m = 0; m < BM; ++m) {
      float4 xv = *reinterpret_cast<const float4*>(&xs[m][k]);  // wave-broadcast
      acc[m] = fmaf(xv.x, w0, acc[m]);
      acc[m] = fmaf(xv.y, w1, acc[m]);
      acc[m] = fmaf(xv.z, w2, acc[m]);
      acc[m] = fmaf(xv.w, w3, acc[m]);
    }
  }

  const float bias = (tid < DD) ? b_src[c] : b_dst[c];
  float* dstp = (tid < DD) ? fs : fd;
#pragma unroll
  for (int m = 0; m < BM; ++m) {
    int node = block0 + m;
    if (node < n) dstp[(size_t)node * DD + c] = acc[m] + bias;
  }
}

// ---------------------------------------------------------------------------
// K2: degree count per destination node
// ---------------------------------------------------------------------------
__global__ __launch_bounds__(256) void count_kernel(const int* __restrict__ dst,
                                                    int* __restrict__ count, int ecount) {
  int e = blockIdx.x * 256 + threadIdx.x;
  if (e < ecount) atomicAdd(&count[dst[e]], 1);
}

// ---------------------------------------------------------------------------
// K3: single-block exclusive scan (wave shfl scan + cross-wave LDS), n<=~1e6
// writes offsets[0..n] and a mutable copy in cursor[0..n-1]
// ---------------------------------------------------------------------------
__global__ __launch_bounds__(1024) void scan_kernel(const int* __restrict__ count,
                                                    int* __restrict__ offsets,
                                                    int* __restrict__ cursor, int n) {
  __shared__ int wsum[16];
  __shared__ int s_carry;
  const int tid = threadIdx.x;
  const int lane = tid & 63;
  const int wid = tid >> 6;
  if (tid == 0) s_carry = 0;
  __syncthreads();

  for (int base = 0; base < n; base += 1024) {
    int i = base + tid;
    int v = (i < n) ? count[i] : 0;
    // wave-inclusive scan
    int incl = v;
#pragma unroll
    for (int off = 1; off < 64; off <<= 1) {
      int t = __shfl_up(incl, (unsigned)off, 64);
      if (lane >= off) incl += t;
    }
    if (lane == 63) wsum[wid] = incl;
    __syncthreads();
    int wpre = 0;
    for (int w = 0; w < wid; ++w) wpre += wsum[w];
    int excl = incl - v + wpre + s_carry;
    if (i < n) {
      offsets[i] = excl;
      cursor[i] = excl;
    }
    __syncthreads();  // everyone done reading s_carry / wsum
    if (tid == 1023) s_carry += wpre + incl;  // total of this chunk
    __syncthreads();
  }
  if (tid == 0) offsets[n] = s_carry;
}

// ---------------------------------------------------------------------------
// K4: scatter edges into CSR slots (per-dst lists of source node ids)
// ---------------------------------------------------------------------------
__global__ __launch_bounds__(256) void scatter_kernel(const int* __restrict__ src,
                                                      const int* __restrict__ dst,
                                                      int* __restrict__ cursor,
                                                      int* __restrict__ edge_src, int ecount) {
  int e = blockIdx.x * 256 + threadIdx.x;
  if (e < ecount) {
    int pos = atomicAdd(&cursor[dst[e]], 1);
    edge_src[pos] = src[e];
  }
}

// ---------------------------------------------------------------------------
// K5: per-node fused GATv2 (online softmax + weighted aggregation)
// 1 wave per node, 4 nodes per 256-thread block.
// lane owns dims {2*lane, 2*lane+1}; head = lane>>3; logit reduced via
// shfl_xor within each 8-lane head group.
// ---------------------------------------------------------------------------
__global__ __launch_bounds__(256) void node_kernel(const float* __restrict__ fs,
                                                   const float* __restrict__ fd,
                                                   const float* __restrict__ attn_w,
                                                   const int* __restrict__ offsets,
                                                   const int* __restrict__ edge_src,
                                                   float* __restrict__ out, int n) {
  const int wid = threadIdx.x >> 6;
  const int lane = threadIdx.x & 63;
  const int node = blockIdx.x * 4 + wid;
  if (node >= n) return;

  const int d0 = lane * 2;
  const float2 aw = *reinterpret_cast<const float2*>(&attn_w[d0]);       // (H,DP) flat
  const float2 fdv = *reinterpret_cast<const float2*>(&fd[(size_t)node * DD + d0]);

  const int e0 = offsets[node];
  const int e1 = offsets[node + 1];

  float m = -1e30f;
  float denom = 0.f;
  float2 acc = make_float2(0.f, 0.f);

  for (int e = e0; e < e1; ++e) {
    int s = edge_src[e];
    float2 fsv = *reinterpret_cast<const float2*>(&fs[(size_t)s * DD + d0]);
    float t0 = fsv.x + fdv.x;
    t0 = (t0 > 0.f) ? t0 : t0 * SLOPE;
    float t1 = fsv.y + fdv.y;
    t1 = (t1 > 0.f) ? t1 : t1 * SLOPE;
    float part = aw.x * t0 + aw.y * t1;
    // reduce over the 8 lanes of this head (16 dims, 2 per lane)
    part += __shfl_xor(part, 1, 64);
    part += __shfl_xor(part, 2, 64);
    part += __shfl_xor(part, 4, 64);
    const float logit = part;

    float mnew = fmaxf(m, logit);
    float scale = __expf(m - mnew);   // 0 on first edge (m=-1e30)
    float p = __expf(logit - mnew);
    denom = denom * scale + p;
    acc.x = acc.x * scale + p * fsv.x;
    acc.y = acc.y * scale + p * fsv.y;
    m = mnew;
  }

  float inv = (denom > 0.f) ? 1.f / denom : 0.f;
  float2 o = make_float2(acc.x * inv, acc.y * inv);
  *reinterpret_cast<float2*>(&out[(size_t)node * DD + d0]) = o;
}

// ---------------------------------------------------------------------------
extern "C" void kernel_launch(void* const* d_in, const int* in_sizes, int n_in,
                              void* d_out, int out_size, void* d_ws, size_t ws_size,
                              hipStream_t stream) {
  const float* x     = (const float*)d_in[0];
  const float* w_src = (const float*)d_in[1];
  const float* b_src = (const float*)d_in[2];
  const float* w_dst = (const float*)d_in[3];
  const float* b_dst = (const float*)d_in[4];
  const float* attn_w = (const float*)d_in[5];
  const int* src = (const int*)d_in[6];
  const int* dst = (const int*)d_in[7];
  float* out = (float*)d_out;

  const int n = in_sizes[0] / DD;     // 50000
  const int ecount = in_sizes[6];     // 650000

  // workspace carve-up
  size_t off = 0;
  float* fs = (float*)((char*)d_ws + off); off += (size_t)n * DD * sizeof(float);
  float* fd = (float*)((char*)d_ws + off); off += (size_t)n * DD * sizeof(float);
  int* edge_src = (int*)((char*)d_ws + off); off += (size_t)ecount * sizeof(int);
  int* offsets  = (int*)((char*)d_ws + off); off += (size_t)(n + 1) * sizeof(int);
  int* cursor   = (int*)((char*)d_ws + off); off += (size_t)n * sizeof(int);
  int* count    = (int*)((char*)d_ws + off); off += (size_t)n * sizeof(int);
  (void)ws_size;

  hipMemsetAsync(count, 0, (size_t)n * sizeof(int), stream);

  proj_kernel<<<(n + BM - 1) / BM, 256, 0, stream>>>(x, w_src, b_src, w_dst, b_dst, fs, fd, n);
  count_kernel<<<(ecount + 255) / 256, 256, 0, stream>>>(dst, count, ecount);
  scan_kernel<<<1, 1024, 0, stream>>>(count, offsets, cursor, n);
  scatter_kernel<<<(ecount + 255) / 256, 256, 0, stream>>>(src, dst, cursor, edge_src, ecount);
  node_kernel<<<(n + 3) / 4, 256, 0, stream>>>(fs, fd, attn_w, offsets, edge_src, out, n);
}

// Round 3
// 270.639 us; speedup vs baseline: 1.3687x; 1.3687x over previous
//
#include <hip/hip_runtime.h>
#include <hip/hip_bf16.h>

#define HH 8
#define DP 16
#define DD 128
#define SLOPE 0.2f

// ---------------------------------------------------------------------------
// K1: fused projection  fs = x@w_src + b_src ; fd = x@w_dst + b_dst
// block = 256 threads. c = tid&127 (column), half = tid>>7 (node sub-tile).
// Each thread computes column c of BOTH fs and fd for 16 nodes.
// Per k-quad: 16 ds_read_b128 (broadcast) + 8 coalesced w loads + 128 FMA
// -> FMA-bound (vs 32 reads/128 FMA before = LDS-bound).
// ---------------------------------------------------------------------------
#define BM 32
__global__ __launch_bounds__(256) void proj_kernel(
    const float* __restrict__ x,
    const float* __restrict__ w_src, const float* __restrict__ b_src,
    const float* __restrict__ w_dst, const float* __restrict__ b_dst,
    float* __restrict__ fs, float* __restrict__ fd, int n) {
  __shared__ float xs[BM][DD];
  const int tid = threadIdx.x;
  const int block0 = blockIdx.x * BM;

  // stage x tile: BM*128 floats = 1024 float4, 256 threads -> 4 each
  for (int i = tid; i < BM * DD / 4; i += 256) {
    int m = i >> 5;
    int k = (i & 31) << 2;
    int node = block0 + m;
    float4 v = make_float4(0.f, 0.f, 0.f, 0.f);
    if (node < n) v = *reinterpret_cast<const float4*>(x + (size_t)node * DD + k);
    *reinterpret_cast<float4*>(&xs[m][k]) = v;
  }
  __syncthreads();

  const int c = tid & (DD - 1);
  const int half = tid >> 7;          // 0 or 1: nodes [half*16, half*16+16)
  const int m0 = half * 16;

  float acc_s[16], acc_d[16];
#pragma unroll
  for (int m = 0; m < 16; ++m) { acc_s[m] = 0.f; acc_d[m] = 0.f; }

  for (int k = 0; k < DD; k += 4) {
    float ws0 = w_src[(k + 0) * DD + c];
    float ws1 = w_src[(k + 1) * DD + c];
    float ws2 = w_src[(k + 2) * DD + c];
    float ws3 = w_src[(k + 3) * DD + c];
    float wd0 = w_dst[(k + 0) * DD + c];
    float wd1 = w_dst[(k + 1) * DD + c];
    float wd2 = w_dst[(k + 2) * DD + c];
    float wd3 = w_dst[(k + 3) * DD + c];
#pragma unroll
    for (int m = 0; m < 16; ++m) {
      float4 xv = *reinterpret_cast<const float4*>(&xs[m0 + m][k]);  // broadcast
      acc_s[m] = fmaf(xv.x, ws0, acc_s[m]);
      acc_s[m] = fmaf(xv.y, ws1, acc_s[m]);
      acc_s[m] = fmaf(xv.z, ws2, acc_s[m]);
      acc_s[m] = fmaf(xv.w, ws3, acc_s[m]);
      acc_d[m] = fmaf(xv.x, wd0, acc_d[m]);
      acc_d[m] = fmaf(xv.y, wd1, acc_d[m]);
      acc_d[m] = fmaf(xv.z, wd2, acc_d[m]);
      acc_d[m] = fmaf(xv.w, wd3, acc_d[m]);
    }
  }

  const float bs = b_src[c];
  const float bd = b_dst[c];
#pragma unroll
  for (int m = 0; m < 16; ++m) {
    int node = block0 + m0 + m;
    if (node < n) {
      fs[(size_t)node * DD + c] = acc_s[m] + bs;
      fd[(size_t)node * DD + c] = acc_d[m] + bd;
    }
  }
}

// ---------------------------------------------------------------------------
// K2: degree count per destination node
// ---------------------------------------------------------------------------
__global__ __launch_bounds__(256) void count_kernel(const int* __restrict__ dst,
                                                    int* __restrict__ count, int ecount) {
  int e = blockIdx.x * 256 + threadIdx.x;
  if (e < ecount) atomicAdd(&count[dst[e]], 1);
}

// ---------------------------------------------------------------------------
// K3: wave-parallel CSR range allocation. Ranges need NOT be sorted by node:
// each wave scans 256 counts (4x64 shfl-scan with carry), grabs a base with a
// single atomicAdd on a global cursor, writes per-node start into cursor[].
// ---------------------------------------------------------------------------
__global__ __launch_bounds__(256) void alloc_kernel(const int* __restrict__ count,
                                                    int* __restrict__ cursor,
                                                    int* __restrict__ total, int n) {
  const int lane = threadIdx.x & 63;
  const int wid = threadIdx.x >> 6;
  const int wave = blockIdx.x * 4 + wid;
  const int i0 = wave * 256;

  int excl[4];
  int carry = 0;
#pragma unroll
  for (int j = 0; j < 4; ++j) {
    int i = i0 + j * 64 + lane;
    int v = (i < n) ? count[i] : 0;
    int incl = v;
#pragma unroll
    for (int off = 1; off < 64; off <<= 1) {
      int t = __shfl_up(incl, (unsigned)off, 64);
      if (lane >= off) incl += t;
    }
    excl[j] = carry + incl - v;
    carry += __shfl(incl, 63, 64);
  }
  int base = 0;
  if (lane == 63) base = atomicAdd(total, carry);
  base = __shfl(base, 63, 64);
#pragma unroll
  for (int j = 0; j < 4; ++j) {
    int i = i0 + j * 64 + lane;
    if (i < n) cursor[i] = base + excl[j];
  }
}

// ---------------------------------------------------------------------------
// K4: scatter edges into CSR slots; cursor[i] ends at range end.
// ---------------------------------------------------------------------------
__global__ __launch_bounds__(256) void scatter_kernel(const int* __restrict__ src,
                                                      const int* __restrict__ dst,
                                                      int* __restrict__ cursor,
                                                      int* __restrict__ edge_src, int ecount) {
  int e = blockIdx.x * 256 + threadIdx.x;
  if (e < ecount) {
    int pos = atomicAdd(&cursor[dst[e]], 1);
    edge_src[pos] = src[e];
  }
}

// ---------------------------------------------------------------------------
// K5: per-node fused GATv2 (online softmax + weighted aggregation)
// 1 wave per node, 4 nodes per block. Dual independent online-softmax chains
// (even/odd edges) merged at the end -> 2x memory-level parallelism.
// e0 = cursor[node] - count[node] (cursor holds range END post-scatter).
// ---------------------------------------------------------------------------
__global__ __launch_bounds__(256) void node_kernel(const float* __restrict__ fs,
                                                   const float* __restrict__ fd,
                                                   const float* __restrict__ attn_w,
                                                   const int* __restrict__ cursor,
                                                   const int* __restrict__ count,
                                                   const int* __restrict__ edge_src,
                                                   float* __restrict__ out, int n) {
  const int wid = threadIdx.x >> 6;
  const int lane = threadIdx.x & 63;
  const int node = blockIdx.x * 4 + wid;
  if (node >= n) return;

  const int d0 = lane * 2;
  const float2 aw = *reinterpret_cast<const float2*>(&attn_w[d0]);
  const float2 fdv = *reinterpret_cast<const float2*>(&fd[(size_t)node * DD + d0]);

  const int e1 = cursor[node];
  const int e0 = e1 - count[node];

  float m0 = -1e30f, m1 = -1e30f;
  float den0 = 0.f, den1 = 0.f;
  float2 ac0 = make_float2(0.f, 0.f), ac1 = make_float2(0.f, 0.f);

  int e = e0;
  for (; e + 1 < e1; e += 2) {
    int sA = edge_src[e];
    int sB = edge_src[e + 1];
    float2 fA = *reinterpret_cast<const float2*>(&fs[(size_t)sA * DD + d0]);
    float2 fB = *reinterpret_cast<const float2*>(&fs[(size_t)sB * DD + d0]);

    float a0 = fA.x + fdv.x; a0 = (a0 > 0.f) ? a0 : a0 * SLOPE;
    float a1 = fA.y + fdv.y; a1 = (a1 > 0.f) ? a1 : a1 * SLOPE;
    float b0 = fB.x + fdv.x; b0 = (b0 > 0.f) ? b0 : b0 * SLOPE;
    float b1 = fB.y + fdv.y; b1 = (b1 > 0.f) ? b1 : b1 * SLOPE;
    float pA = aw.x * a0 + aw.y * a1;
    float pB = aw.x * b0 + aw.y * b1;
    pA += __shfl_xor(pA, 1, 64); pB += __shfl_xor(pB, 1, 64);
    pA += __shfl_xor(pA, 2, 64); pB += __shfl_xor(pB, 2, 64);
    pA += __shfl_xor(pA, 4, 64); pB += __shfl_xor(pB, 4, 64);

    float mA = fmaxf(m0, pA);
    float scA = __expf(m0 - mA);
    float eA = __expf(pA - mA);
    den0 = den0 * scA + eA;
    ac0.x = ac0.x * scA + eA * fA.x;
    ac0.y = ac0.y * scA + eA * fA.y;
    m0 = mA;

    float mB = fmaxf(m1, pB);
    float scB = __expf(m1 - mB);
    float eB = __expf(pB - mB);
    den1 = den1 * scB + eB;
    ac1.x = ac1.x * scB + eB * fB.x;
    ac1.y = ac1.y * scB + eB * fB.y;
    m1 = mB;
  }
  if (e < e1) {  // tail edge -> chain 0
    int sA = edge_src[e];
    float2 fA = *reinterpret_cast<const float2*>(&fs[(size_t)sA * DD + d0]);
    float a0 = fA.x + fdv.x; a0 = (a0 > 0.f) ? a0 : a0 * SLOPE;
    float a1 = fA.y + fdv.y; a1 = (a1 > 0.f) ? a1 : a1 * SLOPE;
    float pA = aw.x * a0 + aw.y * a1;
    pA += __shfl_xor(pA, 1, 64);
    pA += __shfl_xor(pA, 2, 64);
    pA += __shfl_xor(pA, 4, 64);
    float mA = fmaxf(m0, pA);
    float scA = __expf(m0 - mA);
    float eA = __expf(pA - mA);
    den0 = den0 * scA + eA;
    ac0.x = ac0.x * scA + eA * fA.x;
    ac0.y = ac0.y * scA + eA * fA.y;
    m0 = mA;
  }

  // merge the two chains
  float M = fmaxf(m0, m1);
  float s0 = __expf(m0 - M);          // 0 if chain empty (m=-1e30)
  float s1 = __expf(m1 - M);
  float denom = den0 * s0 + den1 * s1;
  float ax = ac0.x * s0 + ac1.x * s1;
  float ay = ac0.y * s0 + ac1.y * s1;

  float inv = (denom > 0.f) ? 1.f / denom : 0.f;
  *reinterpret_cast<float2*>(&out[(size_t)node * DD + d0]) =
      make_float2(ax * inv, ay * inv);
}

// ---------------------------------------------------------------------------
extern "C" void kernel_launch(void* const* d_in, const int* in_sizes, int n_in,
                              void* d_out, int out_size, void* d_ws, size_t ws_size,
                              hipStream_t stream) {
  const float* x      = (const float*)d_in[0];
  const float* w_src  = (const float*)d_in[1];
  const float* b_src  = (const float*)d_in[2];
  const float* w_dst  = (const float*)d_in[3];
  const float* b_dst  = (const float*)d_in[4];
  const float* attn_w = (const float*)d_in[5];
  const int* src = (const int*)d_in[6];
  const int* dst = (const int*)d_in[7];
  float* out = (float*)d_out;

  const int n = in_sizes[0] / DD;     // 50000
  const int ecount = in_sizes[6];     // 650000

  size_t off = 0;
  float* fs = (float*)((char*)d_ws + off); off += (size_t)n * DD * sizeof(float);
  float* fd = (float*)((char*)d_ws + off); off += (size_t)n * DD * sizeof(float);
  int* edge_src = (int*)((char*)d_ws + off); off += (size_t)ecount * sizeof(int);
  int* cursor   = (int*)((char*)d_ws + off); off += (size_t)n * sizeof(int);
  int* count    = (int*)((char*)d_ws + off); off += (size_t)n * sizeof(int);
  int* total    = (int*)((char*)d_ws + off); off += sizeof(int);
  (void)ws_size;

  // zero count[n] and total[1] in one shot (adjacent)
  hipMemsetAsync(count, 0, (size_t)(n + 1) * sizeof(int), stream);

  proj_kernel<<<(n + BM - 1) / BM, 256, 0, stream>>>(x, w_src, b_src, w_dst, b_dst, fs, fd, n);
  count_kernel<<<(ecount + 255) / 256, 256, 0, stream>>>(dst, count, ecount);
  alloc_kernel<<<(n + 1023) / 1024, 256, 0, stream>>>(count, cursor, total, n);
  scatter_kernel<<<(ecount + 255) / 256, 256, 0, stream>>>(src, dst, cursor, edge_src, ecount);
  node_kernel<<<(n + 3) / 4, 256, 0, stream>>>(fs, fd, attn_w, cursor, count, edge_src, out, n);
}

// Round 4
// 264.170 us; speedup vs baseline: 1.4022x; 1.0245x over previous
//
#include <hip/hip_runtime.h>
#include <hip/hip_bf16.h>

#define HH 8
#define DP 16
#define DD 128
#define SLOPE 0.2f

// ---------------------------------------------------------------------------
// K1: fused [count | proj] kernel.
// Blocks [0, count_blocks): grid-stride degree count (atomicAdd, L2-bound).
// Blocks [count_blocks, ...): projection fs = x@w_src+b_src ; fd = x@w_dst+b_dst.
//   256 threads, c = tid&127, half = tid>>7 -> 16 nodes each, BM=32/block.
//   Depth-1 register prefetch of next k-quad's 8 w values hides L2 latency
//   under the 128 FMAs of the current quad (round-3 stall was exactly this).
// ---------------------------------------------------------------------------
#define BM 32
#define COUNT_BLOCKS 512
__global__ __launch_bounds__(256) void proj_count_kernel(
    const float* __restrict__ x,
    const float* __restrict__ w_src, const float* __restrict__ b_src,
    const float* __restrict__ w_dst, const float* __restrict__ b_dst,
    float* __restrict__ fs, float* __restrict__ fd, int n,
    const int* __restrict__ dst, int* __restrict__ count, int ecount) {
  __shared__ float xs[BM][DD];
  const int tid = threadIdx.x;

  if (blockIdx.x < COUNT_BLOCKS) {
    // ---- count role ----
    const int stride = COUNT_BLOCKS * 256;
    for (int e = blockIdx.x * 256 + tid; e < ecount; e += stride)
      atomicAdd(&count[dst[e]], 1);
    return;
  }

  // ---- proj role ----
  const int block0 = (blockIdx.x - COUNT_BLOCKS) * BM;

  for (int i = tid; i < BM * DD / 4; i += 256) {
    int m = i >> 5;
    int k = (i & 31) << 2;
    int node = block0 + m;
    float4 v = make_float4(0.f, 0.f, 0.f, 0.f);
    if (node < n) v = *reinterpret_cast<const float4*>(x + (size_t)node * DD + k);
    *reinterpret_cast<float4*>(&xs[m][k]) = v;
  }
  __syncthreads();

  const int c = tid & (DD - 1);
  const int m0 = (tid >> 7) * 16;

  float acc_s[16], acc_d[16];
#pragma unroll
  for (int m = 0; m < 16; ++m) { acc_s[m] = 0.f; acc_d[m] = 0.f; }

  // prefetch k-quad 0
  float ws0 = w_src[0 * DD + c], ws1 = w_src[1 * DD + c];
  float ws2 = w_src[2 * DD + c], ws3 = w_src[3 * DD + c];
  float wd0 = w_dst[0 * DD + c], wd1 = w_dst[1 * DD + c];
  float wd2 = w_dst[2 * DD + c], wd3 = w_dst[3 * DD + c];

  for (int k = 0; k < DD; k += 4) {
    const int kn = (k + 4) & (DD - 1);  // wraps to 0 on last iter (harmless)
    float nws0 = w_src[(kn + 0) * DD + c], nws1 = w_src[(kn + 1) * DD + c];
    float nws2 = w_src[(kn + 2) * DD + c], nws3 = w_src[(kn + 3) * DD + c];
    float nwd0 = w_dst[(kn + 0) * DD + c], nwd1 = w_dst[(kn + 1) * DD + c];
    float nwd2 = w_dst[(kn + 2) * DD + c], nwd3 = w_dst[(kn + 3) * DD + c];
#pragma unroll
    for (int m = 0; m < 16; ++m) {
      float4 xv = *reinterpret_cast<const float4*>(&xs[m0 + m][k]);  // broadcast
      acc_s[m] = fmaf(xv.x, ws0, acc_s[m]);
      acc_s[m] = fmaf(xv.y, ws1, acc_s[m]);
      acc_s[m] = fmaf(xv.z, ws2, acc_s[m]);
      acc_s[m] = fmaf(xv.w, ws3, acc_s[m]);
      acc_d[m] = fmaf(xv.x, wd0, acc_d[m]);
      acc_d[m] = fmaf(xv.y, wd1, acc_d[m]);
      acc_d[m] = fmaf(xv.z, wd2, acc_d[m]);
      acc_d[m] = fmaf(xv.w, wd3, acc_d[m]);
    }
    ws0 = nws0; ws1 = nws1; ws2 = nws2; ws3 = nws3;
    wd0 = nwd0; wd1 = nwd1; wd2 = nwd2; wd3 = nwd3;
  }

  const float bs = b_src[c];
  const float bd = b_dst[c];
#pragma unroll
  for (int m = 0; m < 16; ++m) {
    int node = block0 + m0 + m;
    if (node < n) {
      fs[(size_t)node * DD + c] = acc_s[m] + bs;
      fd[(size_t)node * DD + c] = acc_d[m] + bd;
    }
  }
}

// ---------------------------------------------------------------------------
// K2: wave-parallel CSR range allocation (ranges need not be node-sorted).
// ---------------------------------------------------------------------------
__global__ __launch_bounds__(256) void alloc_kernel(const int* __restrict__ count,
                                                    int* __restrict__ cursor,
                                                    int* __restrict__ total, int n) {
  const int lane = threadIdx.x & 63;
  const int wid = threadIdx.x >> 6;
  const int wave = blockIdx.x * 4 + wid;
  const int i0 = wave * 256;

  int excl[4];
  int carry = 0;
#pragma unroll
  for (int j = 0; j < 4; ++j) {
    int i = i0 + j * 64 + lane;
    int v = (i < n) ? count[i] : 0;
    int incl = v;
#pragma unroll
    for (int off = 1; off < 64; off <<= 1) {
      int t = __shfl_up(incl, (unsigned)off, 64);
      if (lane >= off) incl += t;
    }
    excl[j] = carry + incl - v;
    carry += __shfl(incl, 63, 64);
  }
  int base = 0;
  if (lane == 63) base = atomicAdd(total, carry);
  base = __shfl(base, 63, 64);
#pragma unroll
  for (int j = 0; j < 4; ++j) {
    int i = i0 + j * 64 + lane;
    if (i < n) cursor[i] = base + excl[j];
  }
}

// ---------------------------------------------------------------------------
// K3: scatter edges into CSR slots; cursor[i] ends at range end.
// ---------------------------------------------------------------------------
__global__ __launch_bounds__(256) void scatter_kernel(const int* __restrict__ src,
                                                      const int* __restrict__ dst,
                                                      int* __restrict__ cursor,
                                                      int* __restrict__ edge_src, int ecount) {
  int e = blockIdx.x * 256 + threadIdx.x;
  if (e < ecount) {
    int pos = atomicAdd(&cursor[dst[e]], 1);
    edge_src[pos] = src[e];
  }
}

// ---------------------------------------------------------------------------
// K4: per-node fused GATv2 (online softmax + weighted aggregation).
// 1 wave per node, 4 nodes per block. FOUR independent online-softmax chains
// (4 gathers in flight) merged at the end. e0 = cursor[node]-count[node].
// ---------------------------------------------------------------------------
__global__ __launch_bounds__(256) void node_kernel(const float* __restrict__ fs,
                                                   const float* __restrict__ fd,
                                                   const float* __restrict__ attn_w,
                                                   const int* __restrict__ cursor,
                                                   const int* __restrict__ count,
                                                   const int* __restrict__ edge_src,
                                                   float* __restrict__ out, int n) {
  const int wid = threadIdx.x >> 6;
  const int lane = threadIdx.x & 63;
  const int node = blockIdx.x * 4 + wid;
  if (node >= n) return;

  const int d0 = lane * 2;
  const float2 aw = *reinterpret_cast<const float2*>(&attn_w[d0]);
  const float2 fdv = *reinterpret_cast<const float2*>(&fd[(size_t)node * DD + d0]);

  const int e1 = cursor[node];
  const int e0 = e1 - count[node];

  float mx[4] = {-1e30f, -1e30f, -1e30f, -1e30f};
  float den[4] = {0.f, 0.f, 0.f, 0.f};
  float2 ac[4] = {{0.f, 0.f}, {0.f, 0.f}, {0.f, 0.f}, {0.f, 0.f}};

  auto logit_of = [&](float2 fsv) -> float {
    float t0 = fsv.x + fdv.x; t0 = (t0 > 0.f) ? t0 : t0 * SLOPE;
    float t1 = fsv.y + fdv.y; t1 = (t1 > 0.f) ? t1 : t1 * SLOPE;
    float p = aw.x * t0 + aw.y * t1;
    p += __shfl_xor(p, 1, 64);
    p += __shfl_xor(p, 2, 64);
    p += __shfl_xor(p, 4, 64);
    return p;
  };
  auto upd = [](float& m, float& dn, float2& a, float logit, float2 fsv) {
    float mn = fmaxf(m, logit);
    float sc = __expf(m - mn);
    float p = __expf(logit - mn);
    dn = dn * sc + p;
    a.x = a.x * sc + p * fsv.x;
    a.y = a.y * sc + p * fsv.y;
    m = mn;
  };

  int e = e0;
  for (; e + 3 < e1; e += 4) {
    int s0 = edge_src[e], s1 = edge_src[e + 1];
    int s2 = edge_src[e + 2], s3 = edge_src[e + 3];
    float2 f0 = *reinterpret_cast<const float2*>(&fs[(size_t)s0 * DD + d0]);
    float2 f1 = *reinterpret_cast<const float2*>(&fs[(size_t)s1 * DD + d0]);
    float2 f2 = *reinterpret_cast<const float2*>(&fs[(size_t)s2 * DD + d0]);
    float2 f3 = *reinterpret_cast<const float2*>(&fs[(size_t)s3 * DD + d0]);
    float l0 = logit_of(f0), l1 = logit_of(f1);
    float l2 = logit_of(f2), l3 = logit_of(f3);
    upd(mx[0], den[0], ac[0], l0, f0);
    upd(mx[1], den[1], ac[1], l1, f1);
    upd(mx[2], den[2], ac[2], l2, f2);
    upd(mx[3], den[3], ac[3], l3, f3);
  }
  for (; e < e1; ++e) {
    int s0 = edge_src[e];
    float2 f0 = *reinterpret_cast<const float2*>(&fs[(size_t)s0 * DD + d0]);
    float l0 = logit_of(f0);
    upd(mx[0], den[0], ac[0], l0, f0);
  }

  // merge 4 chains
  float M = fmaxf(fmaxf(mx[0], mx[1]), fmaxf(mx[2], mx[3]));
  float denom = 0.f, ax = 0.f, ay = 0.f;
#pragma unroll
  for (int j = 0; j < 4; ++j) {
    float s = __expf(mx[j] - M);
    denom += den[j] * s;
    ax += ac[j].x * s;
    ay += ac[j].y * s;
  }

  float inv = (denom > 0.f) ? 1.f / denom : 0.f;
  *reinterpret_cast<float2*>(&out[(size_t)node * DD + d0]) =
      make_float2(ax * inv, ay * inv);
}

// ---------------------------------------------------------------------------
extern "C" void kernel_launch(void* const* d_in, const int* in_sizes, int n_in,
                              void* d_out, int out_size, void* d_ws, size_t ws_size,
                              hipStream_t stream) {
  const float* x      = (const float*)d_in[0];
  const float* w_src  = (const float*)d_in[1];
  const float* b_src  = (const float*)d_in[2];
  const float* w_dst  = (const float*)d_in[3];
  const float* b_dst  = (const float*)d_in[4];
  const float* attn_w = (const float*)d_in[5];
  const int* src = (const int*)d_in[6];
  const int* dst = (const int*)d_in[7];
  float* out = (float*)d_out;

  const int n = in_sizes[0] / DD;     // 50000
  const int ecount = in_sizes[6];     // 650000

  size_t off = 0;
  float* fs = (float*)((char*)d_ws + off); off += (size_t)n * DD * sizeof(float);
  float* fd = (float*)((char*)d_ws + off); off += (size_t)n * DD * sizeof(float);
  int* edge_src = (int*)((char*)d_ws + off); off += (size_t)ecount * sizeof(int);
  int* cursor   = (int*)((char*)d_ws + off); off += (size_t)n * sizeof(int);
  int* count    = (int*)((char*)d_ws + off); off += (size_t)n * sizeof(int);
  int* total    = (int*)((char*)d_ws + off); off += sizeof(int);
  (void)ws_size;

  // zero count[n] and total[1] in one shot (adjacent)
  hipMemsetAsync(count, 0, (size_t)(n + 1) * sizeof(int), stream);

  const int proj_blocks = (n + BM - 1) / BM;
  proj_count_kernel<<<COUNT_BLOCKS + proj_blocks, 256, 0, stream>>>(
      x, w_src, b_src, w_dst, b_dst, fs, fd, n, dst, count, ecount);
  alloc_kernel<<<(n + 1023) / 1024, 256, 0, stream>>>(count, cursor, total, n);
  scatter_kernel<<<(ecount + 255) / 256, 256, 0, stream>>>(src, dst, cursor, edge_src, ecount);
  node_kernel<<<(n + 3) / 4, 256, 0, stream>>>(fs, fd, attn_w, cursor, count, edge_src, out, n);
}

// Round 5
// 253.652 us; speedup vs baseline: 1.4603x; 1.0415x over previous
//
#include <hip/hip_runtime.h>
#include <hip/hip_bf16.h>

#define HH 8
#define DP 16
#define DD 128
#define SLOPE 0.2f

// ---------------------------------------------------------------------------
// K1: proj (+ sequential count tail).
// Phase 1: fs = x@w_src+b_src ; fd = x@w_dst+b_dst.
//   256 threads, c = tid&127, 16 nodes/thread, BM=32/block.
//   Depth-1 register prefetch of the next k-quad's 8 w values hides the
//   L2 load-use latency under the 128 FMAs of the current quad.
// Phase 2 (after proj stores): grid-stride degree count (~1.6 edges/thread).
//   Sequential phase, not concurrent roles -> no CU competition (r4 lesson).
// ---------------------------------------------------------------------------
#define BM 32
__global__ __launch_bounds__(256) void proj_count_kernel(
    const float* __restrict__ x,
    const float* __restrict__ w_src, const float* __restrict__ b_src,
    const float* __restrict__ w_dst, const float* __restrict__ b_dst,
    float* __restrict__ fs, float* __restrict__ fd, int n,
    const int* __restrict__ dst, int* __restrict__ count, int ecount) {
  __shared__ float xs[BM][DD];
  const int tid = threadIdx.x;
  const int block0 = blockIdx.x * BM;

  for (int i = tid; i < BM * DD / 4; i += 256) {
    int m = i >> 5;
    int k = (i & 31) << 2;
    int node = block0 + m;
    float4 v = make_float4(0.f, 0.f, 0.f, 0.f);
    if (node < n) v = *reinterpret_cast<const float4*>(x + (size_t)node * DD + k);
    *reinterpret_cast<float4*>(&xs[m][k]) = v;
  }
  __syncthreads();

  const int c = tid & (DD - 1);
  const int m0 = (tid >> 7) * 16;

  float acc_s[16], acc_d[16];
#pragma unroll
  for (int m = 0; m < 16; ++m) { acc_s[m] = 0.f; acc_d[m] = 0.f; }

  // prefetch k-quad 0
  float ws0 = w_src[0 * DD + c], ws1 = w_src[1 * DD + c];
  float ws2 = w_src[2 * DD + c], ws3 = w_src[3 * DD + c];
  float wd0 = w_dst[0 * DD + c], wd1 = w_dst[1 * DD + c];
  float wd2 = w_dst[2 * DD + c], wd3 = w_dst[3 * DD + c];

  for (int k = 0; k < DD; k += 4) {
    const int kn = (k + 4) & (DD - 1);  // wraps to 0 on last iter (harmless)
    float nws0 = w_src[(kn + 0) * DD + c], nws1 = w_src[(kn + 1) * DD + c];
    float nws2 = w_src[(kn + 2) * DD + c], nws3 = w_src[(kn + 3) * DD + c];
    float nwd0 = w_dst[(kn + 0) * DD + c], nwd1 = w_dst[(kn + 1) * DD + c];
    float nwd2 = w_dst[(kn + 2) * DD + c], nwd3 = w_dst[(kn + 3) * DD + c];
#pragma unroll
    for (int m = 0; m < 16; ++m) {
      float4 xv = *reinterpret_cast<const float4*>(&xs[m0 + m][k]);  // broadcast
      acc_s[m] = fmaf(xv.x, ws0, acc_s[m]);
      acc_s[m] = fmaf(xv.y, ws1, acc_s[m]);
      acc_s[m] = fmaf(xv.z, ws2, acc_s[m]);
      acc_s[m] = fmaf(xv.w, ws3, acc_s[m]);
      acc_d[m] = fmaf(xv.x, wd0, acc_d[m]);
      acc_d[m] = fmaf(xv.y, wd1, acc_d[m]);
      acc_d[m] = fmaf(xv.z, wd2, acc_d[m]);
      acc_d[m] = fmaf(xv.w, wd3, acc_d[m]);
    }
    ws0 = nws0; ws1 = nws1; ws2 = nws2; ws3 = nws3;
    wd0 = nwd0; wd1 = nwd1; wd2 = nwd2; wd3 = nwd3;
  }

  const float bs = b_src[c];
  const float bd = b_dst[c];
#pragma unroll
  for (int m = 0; m < 16; ++m) {
    int node = block0 + m0 + m;
    if (node < n) {
      fs[(size_t)node * DD + c] = acc_s[m] + bs;
      fd[(size_t)node * DD + c] = acc_d[m] + bd;
    }
  }

  // ---- phase 2: degree count ----
  const int nblocks = (n + BM - 1) / BM;
  const int stride = nblocks * 256;
  for (int e = blockIdx.x * 256 + tid; e < ecount; e += stride)
    atomicAdd(&count[dst[e]], 1);
}

// ---------------------------------------------------------------------------
// K2: wave-parallel CSR range allocation (ranges need not be node-sorted).
// ---------------------------------------------------------------------------
__global__ __launch_bounds__(256) void alloc_kernel(const int* __restrict__ count,
                                                    int* __restrict__ cursor,
                                                    int* __restrict__ total, int n) {
  const int lane = threadIdx.x & 63;
  const int wid = threadIdx.x >> 6;
  const int wave = blockIdx.x * 4 + wid;
  const int i0 = wave * 256;

  int excl[4];
  int carry = 0;
#pragma unroll
  for (int j = 0; j < 4; ++j) {
    int i = i0 + j * 64 + lane;
    int v = (i < n) ? count[i] : 0;
    int incl = v;
#pragma unroll
    for (int off = 1; off < 64; off <<= 1) {
      int t = __shfl_up(incl, (unsigned)off, 64);
      if (lane >= off) incl += t;
    }
    excl[j] = carry + incl - v;
    carry += __shfl(incl, 63, 64);
  }
  int base = 0;
  if (lane == 63) base = atomicAdd(total, carry);
  base = __shfl(base, 63, 64);
#pragma unroll
  for (int j = 0; j < 4; ++j) {
    int i = i0 + j * 64 + lane;
    if (i < n) cursor[i] = base + excl[j];
  }
}

// ---------------------------------------------------------------------------
// K3: scatter edges into CSR slots; cursor[i] ends at range end.
// ---------------------------------------------------------------------------
__global__ __launch_bounds__(256) void scatter_kernel(const int* __restrict__ src,
                                                      const int* __restrict__ dst,
                                                      int* __restrict__ cursor,
                                                      int* __restrict__ edge_src, int ecount) {
  int e = blockIdx.x * 256 + threadIdx.x;
  if (e < ecount) {
    int pos = atomicAdd(&cursor[dst[e]], 1);
    edge_src[pos] = src[e];
  }
}

// ---------------------------------------------------------------------------
// K4: per-node fused GATv2 (online softmax + weighted aggregation).
// 1 wave per node, 4 nodes/block. 4 independent online-softmax chains PLUS a
// depth-1 software pipeline on the gathers: next group's ids+fs rows are in
// flight while the current group's exp/update chain runs -> 8 gathers in
// flight per wave. e0 = cursor[node]-count[node] (cursor = range end).
// ---------------------------------------------------------------------------
__global__ __launch_bounds__(256) void node_kernel(const float* __restrict__ fs,
                                                   const float* __restrict__ fd,
                                                   const float* __restrict__ attn_w,
                                                   const int* __restrict__ cursor,
                                                   const int* __restrict__ count,
                                                   const int* __restrict__ edge_src,
                                                   float* __restrict__ out, int n) {
  const int wid = threadIdx.x >> 6;
  const int lane = threadIdx.x & 63;
  const int node = blockIdx.x * 4 + wid;
  if (node >= n) return;

  const int d0 = lane * 2;
  const float2 aw = *reinterpret_cast<const float2*>(&attn_w[d0]);
  const float2 fdv = *reinterpret_cast<const float2*>(&fd[(size_t)node * DD + d0]);

  const int e1 = cursor[node];
  const int e0 = e1 - count[node];

  float mx[4] = {-1e30f, -1e30f, -1e30f, -1e30f};
  float den[4] = {0.f, 0.f, 0.f, 0.f};
  float2 ac[4] = {{0.f, 0.f}, {0.f, 0.f}, {0.f, 0.f}, {0.f, 0.f}};

  auto logit_of = [&](float2 fsv) -> float {
    float t0 = fsv.x + fdv.x; t0 = (t0 > 0.f) ? t0 : t0 * SLOPE;
    float t1 = fsv.y + fdv.y; t1 = (t1 > 0.f) ? t1 : t1 * SLOPE;
    float p = aw.x * t0 + aw.y * t1;
    p += __shfl_xor(p, 1, 64);
    p += __shfl_xor(p, 2, 64);
    p += __shfl_xor(p, 4, 64);
    return p;
  };
  auto upd = [](float& m, float& dn, float2& a, float logit, float2 fsv) {
    float mn = fmaxf(m, logit);
    float sc = __expf(m - mn);
    float p = __expf(logit - mn);
    dn = dn * sc + p;
    a.x = a.x * sc + p * fsv.x;
    a.y = a.y * sc + p * fsv.y;
    m = mn;
  };
  auto gather = [&](int s) -> float2 {
    return *reinterpret_cast<const float2*>(&fs[(size_t)s * DD + d0]);
  };

  int e = e0;
  const int nfull = (e1 - e0) >> 2;
  if (nfull > 0) {
    float2 f0 = gather(edge_src[e0]);
    float2 f1 = gather(edge_src[e0 + 1]);
    float2 f2 = gather(edge_src[e0 + 2]);
    float2 f3 = gather(edge_src[e0 + 3]);
    for (int g = 1; g < nfull; ++g) {
      const int b = e0 + g * 4;
      // issue next group's gathers before consuming current group
      float2 g0 = gather(edge_src[b]);
      float2 g1 = gather(edge_src[b + 1]);
      float2 g2 = gather(edge_src[b + 2]);
      float2 g3 = gather(edge_src[b + 3]);
      float l0 = logit_of(f0), l1 = logit_of(f1);
      float l2 = logit_of(f2), l3 = logit_of(f3);
      upd(mx[0], den[0], ac[0], l0, f0);
      upd(mx[1], den[1], ac[1], l1, f1);
      upd(mx[2], den[2], ac[2], l2, f2);
      upd(mx[3], den[3], ac[3], l3, f3);
      f0 = g0; f1 = g1; f2 = g2; f3 = g3;
    }
    float l0 = logit_of(f0), l1 = logit_of(f1);
    float l2 = logit_of(f2), l3 = logit_of(f3);
    upd(mx[0], den[0], ac[0], l0, f0);
    upd(mx[1], den[1], ac[1], l1, f1);
    upd(mx[2], den[2], ac[2], l2, f2);
    upd(mx[3], den[3], ac[3], l3, f3);
    e = e0 + nfull * 4;
  }
  for (; e < e1; ++e) {
    float2 f0 = gather(edge_src[e]);
    float l0 = logit_of(f0);
    upd(mx[0], den[0], ac[0], l0, f0);
  }

  // merge 4 chains
  float M = fmaxf(fmaxf(mx[0], mx[1]), fmaxf(mx[2], mx[3]));
  float denom = 0.f, ax = 0.f, ay = 0.f;
#pragma unroll
  for (int j = 0; j < 4; ++j) {
    float s = __expf(mx[j] - M);
    denom += den[j] * s;
    ax += ac[j].x * s;
    ay += ac[j].y * s;
  }

  float inv = (denom > 0.f) ? 1.f / denom : 0.f;
  *reinterpret_cast<float2*>(&out[(size_t)node * DD + d0]) =
      make_float2(ax * inv, ay * inv);
}

// ---------------------------------------------------------------------------
extern "C" void kernel_launch(void* const* d_in, const int* in_sizes, int n_in,
                              void* d_out, int out_size, void* d_ws, size_t ws_size,
                              hipStream_t stream) {
  const float* x      = (const float*)d_in[0];
  const float* w_src  = (const float*)d_in[1];
  const float* b_src  = (const float*)d_in[2];
  const float* w_dst  = (const float*)d_in[3];
  const float* b_dst  = (const float*)d_in[4];
  const float* attn_w = (const float*)d_in[5];
  const int* src = (const int*)d_in[6];
  const int* dst = (const int*)d_in[7];
  float* out = (float*)d_out;

  const int n = in_sizes[0] / DD;     // 50000
  const int ecount = in_sizes[6];     // 650000

  size_t off = 0;
  float* fs = (float*)((char*)d_ws + off); off += (size_t)n * DD * sizeof(float);
  float* fd = (float*)((char*)d_ws + off); off += (size_t)n * DD * sizeof(float);
  int* edge_src = (int*)((char*)d_ws + off); off += (size_t)ecount * sizeof(int);
  int* cursor   = (int*)((char*)d_ws + off); off += (size_t)n * sizeof(int);
  int* count    = (int*)((char*)d_ws + off); off += (size_t)n * sizeof(int);
  int* total    = (int*)((char*)d_ws + off); off += sizeof(int);
  (void)ws_size;

  // zero count[n] and total[1] in one shot (adjacent)
  hipMemsetAsync(count, 0, (size_t)(n + 1) * sizeof(int), stream);

  const int proj_blocks = (n + BM - 1) / BM;
  proj_count_kernel<<<proj_blocks, 256, 0, stream>>>(
      x, w_src, b_src, w_dst, b_dst, fs, fd, n, dst, count, ecount);
  alloc_kernel<<<(n + 1023) / 1024, 256, 0, stream>>>(count, cursor, total, n);
  scatter_kernel<<<(ecount + 255) / 256, 256, 0, stream>>>(src, dst, cursor, edge_src, ecount);
  node_kernel<<<(n + 3) / 4, 256, 0, stream>>>(fs, fd, attn_w, cursor, count, edge_src, out, n);
}